// Round 2
// baseline (650.683 us; speedup 1.0000x reference)
//
#include <hip/hip_runtime.h>
#include <stdint.h>

typedef unsigned short ushort_t;
typedef unsigned int uint_t;
typedef __attribute__((ext_vector_type(8))) short short8;
typedef __attribute__((ext_vector_type(4))) float f32x4;
typedef _Float16 half_t;
typedef __attribute__((ext_vector_type(4))) _Float16 half4;

#define B_N 32
#define C_N 256
#define HALF_N 128
#define H_N 56
#define W_N 56
#define HW_N 3136
#define NPIX (B_N * HW_N)   // 100352
#define EPS_D 1e-5

__device__ __forceinline__ ushort_t sgn_f(float x) {
    return x > 0.f ? (ushort_t)0x3F80 : (x < 0.f ? (ushort_t)0xBF80 : (ushort_t)0);
}
__device__ __forceinline__ ushort_t sgn_d(double x) {
    return x > 0.0 ? (ushort_t)0x3F80 : (x < 0.0 ? (ushort_t)0xBF80 : (ushort_t)0);
}

// ---------------------------------------------------------------------------
// prep: weight sign matrices (bf16 +/-1) + fp64 scales. blocks 0..127 -> w3,
// 128..255 -> w1. Block 0 zeroes the stats accumulators.
// sw3T layout: [o][tap][ci] so conv3 B-frags are contiguous in ci.
// ---------------------------------------------------------------------------
__global__ void prep_kernel(const float* __restrict__ w3, const float* __restrict__ w1,
                            ushort_t* __restrict__ sw3T, ushort_t* __restrict__ sw1,
                            double* __restrict__ scale3, double* __restrict__ scale1,
                            double* __restrict__ sums1, double* __restrict__ sums2) {
    __shared__ double red[128];
    int t = threadIdx.x;          // 128 threads
    int blk = blockIdx.x;         // 256 blocks
    if (blk == 0) {
        sums1[t] = 0.0; sums1[128 + t] = 0.0;
        sums2[t] = 0.0; sums2[128 + t] = 0.0;
    }
    if (blk < 128) {
        int o = blk;
        double acc = 0.0;
        #pragma unroll
        for (int j = 0; j < 9; ++j) {
            float v = w3[o * 1152 + t * 9 + j];     // [o][ci=t][tap=j]
            acc += fabs((double)v);
            sw3T[(o * 9 + j) * 128 + t] = sgn_f(v);
        }
        red[t] = acc; __syncthreads();
        for (int s = 64; s > 0; s >>= 1) { if (t < s) red[t] += red[t + s]; __syncthreads(); }
        if (t == 0) scale3[o] = red[0] / 1152.0;
    } else {
        int o = blk - 128;
        float v = w1[o * 128 + t];
        sw1[o * 128 + t] = sgn_f(v);
        red[t] = fabs((double)v); __syncthreads();
        for (int s = 64; s > 0; s >>= 1) { if (t < s) red[t] += red[t + s]; __syncthreads(); }
        if (t == 0) scale1[o] = red[0] / 128.0;
    }
}

// ---------------------------------------------------------------------------
// sign1: s1L[p][c] = sign(x_shuffled + b1) as bf16 +/-1, channel-last,
// via 64x64 LDS transpose tile. src(c) = (c&1)*128 + (c>>1).
// ---------------------------------------------------------------------------
__global__ void sign1_kernel(const float* __restrict__ x, const float* __restrict__ b1,
                             ushort_t* __restrict__ s1L) {
    __shared__ ushort_t tile[64 * 65];
    int t = threadIdx.x;
    int p0 = blockIdx.x * 64;
    int c0 = blockIdx.y * 64;
    int b = p0 / HW_N;
    int hw0 = p0 % HW_N;     // 3136 % 64 == 0 -> no image crossing in a tile
    #pragma unroll 4
    for (int it = 0; it < 16; ++it) {
        int idx = it * 256 + t;
        int pl = idx & 63, cl = idx >> 6;
        int c = c0 + cl;
        int src = ((c & 1) << 7) + (c >> 1);
        double v = (double)x[((size_t)b * C_N + src) * HW_N + hw0 + pl] + (double)b1[c];
        tile[cl * 65 + pl] = sgn_d(v);
    }
    __syncthreads();
    #pragma unroll 4
    for (int it = 0; it < 16; ++it) {
        int idx = it * 256 + t;
        int cl = idx & 63, pl = idx >> 6;
        s1L[(size_t)(p0 + pl) * C_N + c0 + cl] = tile[cl * 65 + pl];
    }
}

// ---------------------------------------------------------------------------
// conv3: grouped 3x3 binary conv as implicit GEMM (9 taps x K=128).
// Grid (1568, 2). 4 waves/block; wave computes 16 pixels x 64 out-ch.
// Output y1h[o][p] fp16 (exact integers, |K| <= 1152).
// ---------------------------------------------------------------------------
__global__ __launch_bounds__(256) void conv3_kernel(const ushort_t* __restrict__ s1L,
                                                    const ushort_t* __restrict__ sw3T,
                                                    half_t* __restrict__ yh) {
    int g = blockIdx.y;
    int lane = threadIdx.x & 63;
    int wv = threadIdx.x >> 6;
    int ln15 = lane & 15;
    int kq = lane >> 4;
    int m = blockIdx.x * 64 + wv * 16 + ln15;
    int b = m / HW_N;
    int hw = m % HW_N;
    int h = hw / W_N;
    int w = hw % W_N;

    f32x4 acc[4] = {{0.f,0.f,0.f,0.f},{0.f,0.f,0.f,0.f},{0.f,0.f,0.f,0.f},{0.f,0.f,0.f,0.f}};

    for (int tap = 0; tap < 9; ++tap) {
        int kh = tap / 3 - 1;
        int kw = tap % 3 - 1;
        int hh = h + kh, ww = w + kw;
        bool valid = (hh >= 0) && (hh < H_N) && (ww >= 0) && (ww < W_N);
        const ushort_t* abase = s1L + ((size_t)(b * HW_N + hh * W_N + ww) * C_N + g * HALF_N + kq * 8);
        #pragma unroll
        for (int kc = 0; kc < 4; ++kc) {
            short8 afrag = {0,0,0,0,0,0,0,0};
            if (valid) afrag = *reinterpret_cast<const short8*>(abase + kc * 32);
            #pragma unroll
            for (int j = 0; j < 4; ++j) {
                int o = g * 64 + j * 16 + ln15;
                short8 bfrag = *reinterpret_cast<const short8*>(sw3T + ((o * 9 + tap) * 128 + kc * 32 + kq * 8));
                acc[j] = __builtin_amdgcn_mfma_f32_16x16x32_bf16(afrag, bfrag, acc[j], 0, 0, 0);
            }
        }
    }
    int mo = blockIdx.x * 64 + wv * 16 + kq * 4;   // C/D: row = kq*4 + r (pixel), col = ln15
    #pragma unroll
    for (int j = 0; j < 4; ++j) {
        int o = g * 64 + j * 16 + ln15;
        half4 hv = { (half_t)acc[j][0], (half_t)acc[j][1], (half_t)acc[j][2], (half_t)acc[j][3] };
        *reinterpret_cast<half4*>(yh + (size_t)o * NPIX + mo) = hv;
    }
}

// ---------------------------------------------------------------------------
// conv1: grouped 1x1 binary conv, K=128. Same tiling.
// ---------------------------------------------------------------------------
__global__ __launch_bounds__(256) void conv1_kernel(const ushort_t* __restrict__ s3L,
                                                    const ushort_t* __restrict__ sw1,
                                                    half_t* __restrict__ yh) {
    int g = blockIdx.y;
    int lane = threadIdx.x & 63;
    int wv = threadIdx.x >> 6;
    int ln15 = lane & 15;
    int kq = lane >> 4;
    int m = blockIdx.x * 64 + wv * 16 + ln15;
    const ushort_t* abase = s3L + ((size_t)m * C_N + g * HALF_N + kq * 8);

    f32x4 acc[4] = {{0.f,0.f,0.f,0.f},{0.f,0.f,0.f,0.f},{0.f,0.f,0.f,0.f},{0.f,0.f,0.f,0.f}};
    #pragma unroll
    for (int kc = 0; kc < 4; ++kc) {
        short8 afrag = *reinterpret_cast<const short8*>(abase + kc * 32);
        #pragma unroll
        for (int j = 0; j < 4; ++j) {
            int o = g * 64 + j * 16 + ln15;
            short8 bfrag = *reinterpret_cast<const short8*>(sw1 + (o * 128 + kc * 32 + kq * 8));
            acc[j] = __builtin_amdgcn_mfma_f32_16x16x32_bf16(afrag, bfrag, acc[j], 0, 0, 0);
        }
    }
    int mo = blockIdx.x * 64 + wv * 16 + kq * 4;
    #pragma unroll
    for (int j = 0; j < 4; ++j) {
        int o = g * 64 + j * 16 + ln15;
        half4 hv = { (half_t)acc[j][0], (half_t)acc[j][1], (half_t)acc[j][2], (half_t)acc[j][3] };
        *reinterpret_cast<half4*>(yh + (size_t)o * NPIX + mo) = hv;
    }
}

// ---------------------------------------------------------------------------
// stats: per-channel sum / sumsq (fp64 exact; y values are exact ints).
// Grid 1024: c = bx & 127, chunk = bx >> 7 (8 chunks of 12544 pixels).
// ---------------------------------------------------------------------------
__global__ void stats_kernel(const half_t* __restrict__ yh, double* __restrict__ sums) {
    __shared__ double sh[512];
    int t = threadIdx.x;
    int c = blockIdx.x & 127;
    int chunk = blockIdx.x >> 7;
    const half_t* p = yh + (size_t)c * NPIX + chunk * 12544;
    double s = 0.0, s2 = 0.0;
    for (int i = t; i < 12544; i += 256) {
        double d = (double)(float)p[i];
        s += d; s2 += d * d;
    }
    sh[t] = s; sh[256 + t] = s2;
    __syncthreads();
    for (int k = 128; k > 0; k >>= 1) {
        if (t < k) { sh[t] += sh[t + k]; sh[256 + t] += sh[256 + t + k]; }
        __syncthreads();
    }
    if (t == 0) { atomicAdd(&sums[c], sh[0]); atomicAdd(&sums[128 + c], sh[256]); }
}

// ---------------------------------------------------------------------------
// finalize: fold weight scale + BN into affine coef (fp64).
// BN(s*K) = K*(s*r*g) + (be - s*mean*r*g),  r = 1/sqrt(s^2*var + eps)
// ---------------------------------------------------------------------------
__global__ void finalize_kernel(const double* __restrict__ sums, const double* __restrict__ scale,
                                const float* __restrict__ gamma, const float* __restrict__ beta,
                                double* __restrict__ coef) {
    int c = threadIdx.x;  // 128
    double M = (double)NPIX;
    double mean = sums[c] / M;
    double var = sums[128 + c] / M - mean * mean;
    double s = scale[c];
    double r = 1.0 / sqrt(s * s * var + EPS_D);
    double g = (double)gamma[c];
    coef[c] = s * r * g;
    coef[128 + c] = (double)beta[c] - s * mean * r * g;
}

// ---------------------------------------------------------------------------
// x2 value chain (fp64, deterministic; reused bit-identically in out_kernel
// so conv1's signs stay consistent with the epilogue's recomputed x2).
// ---------------------------------------------------------------------------
__device__ __forceinline__ double x2_val(double xs, double K, bool hasy,
                                         const double* __restrict__ coef1, int c,
                                         const float* __restrict__ b2_1, const float* __restrict__ a2,
                                         const float* __restrict__ b2_2, const float* __restrict__ b3_1) {
    double t = hasy ? (coef1[c] * K + coef1[128 + c] + xs) : xs;
    t += (double)b2_1[c];
    double a = (double)a2[c];
    t = (t >= 0.0) ? t : a * t;
    t += (double)b2_2[c];
    t += (double)b3_1[c];
    return t;
}

// ---------------------------------------------------------------------------
// x2s: s3L[p][c] = sign(x2) channel-last via LDS transpose (x2 NOT stored).
// ---------------------------------------------------------------------------
__global__ void x2s_kernel(const float* __restrict__ x, const half_t* __restrict__ y1h,
                           const double* __restrict__ coef1,
                           const float* __restrict__ b2_1, const float* __restrict__ a2,
                           const float* __restrict__ b2_2, const float* __restrict__ b3_1,
                           ushort_t* __restrict__ s3L) {
    __shared__ ushort_t tile[64 * 65];
    int t = threadIdx.x;
    int p0 = blockIdx.x * 64;
    int c0 = blockIdx.y * 64;
    int b = p0 / HW_N;
    int hw0 = p0 % HW_N;
    #pragma unroll 4
    for (int it = 0; it < 16; ++it) {
        int idx = it * 256 + t;
        int pl = idx & 63, cl = idx >> 6;
        int c = c0 + cl;
        int src = ((c & 1) << 7) + (c >> 1);
        int p = p0 + pl;
        double xs = (double)x[((size_t)b * C_N + src) * HW_N + hw0 + pl];
        bool hasy = (c < 128);
        double K = hasy ? (double)(float)y1h[(size_t)c * NPIX + p] : 0.0;
        tile[cl * 65 + pl] = sgn_d(x2_val(xs, K, hasy, coef1, c, b2_1, a2, b2_2, b3_1));
    }
    __syncthreads();
    #pragma unroll 4
    for (int it = 0; it < 16; ++it) {
        int idx = it * 256 + t;
        int cl = idx & 63, pl = idx >> 6;
        s3L[(size_t)(p0 + pl) * C_N + c0 + cl] = tile[cl * 65 + pl];
    }
}

// ---------------------------------------------------------------------------
// out: recompute x2 (same fp64 expr), x3 = BN3(y3)+x2[:, :128], concat,
// prelu(+b4_1, a4)+b4_2, write NCHW fp32. Fully coalesced, no LDS.
// ---------------------------------------------------------------------------
__global__ void out_kernel(const float* __restrict__ x, const half_t* __restrict__ y1h,
                           const half_t* __restrict__ y3h,
                           const double* __restrict__ coef1, const double* __restrict__ coef3,
                           const float* __restrict__ b2_1, const float* __restrict__ a2,
                           const float* __restrict__ b2_2, const float* __restrict__ b3_1,
                           const float* __restrict__ b4_1, const float* __restrict__ a4,
                           const float* __restrict__ b4_2, float* __restrict__ out) {
    int t = threadIdx.x;
    int c = blockIdx.y;
    int p = blockIdx.x * 256 + t;
    int b = p / HW_N;
    int hw = p % HW_N;
    int src = ((c & 1) << 7) + (c >> 1);
    double xs = (double)x[((size_t)b * C_N + src) * HW_N + hw];
    bool h1 = (c < 128);
    double K1 = h1 ? (double)(float)y1h[(size_t)c * NPIX + p] : 0.0;
    double t2 = x2_val(xs, K1, h1, coef1, c, b2_1, a2, b2_2, b3_1);
    double v = t2;
    if (h1) v = coef3[c] * (double)(float)y3h[(size_t)c * NPIX + p] + coef3[128 + c] + t2;
    v += (double)b4_1[c];
    double a = (double)a4[c];
    v = (v >= 0.0) ? v : a * v;
    v += (double)b4_2[c];
    out[((size_t)b * C_N + c) * HW_N + hw] = (float)v;
}

extern "C" void kernel_launch(void* const* d_in, const int* in_sizes, int n_in,
                              void* d_out, int out_size, void* d_ws, size_t ws_size,
                              hipStream_t stream) {
    const float* x    = (const float*)d_in[0];
    const float* w3   = (const float*)d_in[1];
    const float* w1   = (const float*)d_in[2];
    const float* b1   = (const float*)d_in[3];
    const float* g1   = (const float*)d_in[4];
    const float* be1  = (const float*)d_in[5];
    const float* b2_1 = (const float*)d_in[6];
    const float* a2   = (const float*)d_in[7];
    const float* b2_2 = (const float*)d_in[8];
    const float* b3_1 = (const float*)d_in[9];
    const float* g3   = (const float*)d_in[10];
    const float* be3  = (const float*)d_in[11];
    const float* b4_1 = (const float*)d_in[12];
    const float* a4   = (const float*)d_in[13];
    const float* b4_2 = (const float*)d_in[14];

    // workspace layout (~51.7 MB total)
    char* ws = (char*)d_ws;
    half_t*   y1h    = (half_t*)(ws + 0);                 // 128*NPIX*2 = 25,690,112
    half_t*   y3h    = (half_t*)(ws + 25690112);          // 25,690,112
    ushort_t* sw3T   = (ushort_t*)(ws + 51380224);        // 294,912
    ushort_t* sw1    = (ushort_t*)(ws + 51675136);        // 32,768
    double*   scale3 = (double*)(ws + 51707904);          // 1,024
    double*   scale1 = (double*)(ws + 51708928);          // 1,024
    double*   sums1  = (double*)(ws + 51709952);          // 2,048
    double*   sums2  = (double*)(ws + 51712000);          // 2,048
    double*   coef1  = (double*)(ws + 51714048);          // 2,048
    double*   coef3  = (double*)(ws + 51716096);          // 2,048

    // sign buffers (bf16 +/-1, 51.4 MB) live in d_out (102.7 MB fp32),
    // fully consumed before out_kernel overwrites d_out.
    ushort_t* sbuf = (ushort_t*)d_out;
    float*    outp = (float*)d_out;

    prep_kernel<<<256, 128, 0, stream>>>(w3, w1, sw3T, sw1, scale3, scale1, sums1, sums2);
    sign1_kernel<<<dim3(NPIX / 64, 4), 256, 0, stream>>>(x, b1, sbuf);
    conv3_kernel<<<dim3(NPIX / 64, 2), 256, 0, stream>>>(sbuf, sw3T, y1h);
    stats_kernel<<<1024, 256, 0, stream>>>(y1h, sums1);
    finalize_kernel<<<1, 128, 0, stream>>>(sums1, scale3, g1, be1, coef1);
    x2s_kernel<<<dim3(NPIX / 64, 4), 256, 0, stream>>>(x, y1h, coef1, b2_1, a2, b2_2, b3_1, sbuf);
    conv1_kernel<<<dim3(NPIX / 64, 2), 256, 0, stream>>>(sbuf, sw1, y3h);
    stats_kernel<<<1024, 256, 0, stream>>>(y3h, sums2);
    finalize_kernel<<<1, 128, 0, stream>>>(sums2, scale1, g3, be3, coef3);
    out_kernel<<<dim3(NPIX / 256, 256), 256, 0, stream>>>(x, y1h, y3h, coef1, coef3,
                                                          b2_1, a2, b2_2, b3_1, b4_1, a4, b4_2, outp);
}

// Round 3
// 451.175 us; speedup vs baseline: 1.4422x; 1.4422x over previous
//
#include <hip/hip_runtime.h>
#include <stdint.h>

typedef unsigned short ushort_t;
typedef unsigned int uint_t;
typedef _Float16 half_t;

#define B_N 32
#define C_N 256
#define HALF_N 128
#define H_N 56
#define W_N 56
#define HW_N 3136
#define NPIX (B_N * HW_N)   // 100352
#define EPS_D 1e-5
#define W3STRIDE 48         // dwords per out-ch (36 used, padded for alignment)
#define W1STRIDE 8          // dwords per out-ch (4 used)

// ---------------------------------------------------------------------------
// prep: pack weight sign bits via ballot + fp64 scales.
// blocks 0..127 -> w3 (o=blk), 128..255 -> w1. Block 0 zeroes stats buffers.
// Bit convention: bit=1 means value>0 ("+1"); zero weight treated as -1
// (error bound: count*scale ~ 5e-4, negligible; P(w==0) ~ 0).
// wbits3[(o)*48 + tap*4 + word], word = ci>>5, bit = ci&31.
// ---------------------------------------------------------------------------
__global__ void prep_kernel(const float* __restrict__ w3, const float* __restrict__ w1,
                            uint_t* __restrict__ wbits3, uint_t* __restrict__ wbits1,
                            double* __restrict__ scale3, double* __restrict__ scale1,
                            double* __restrict__ sums1, double* __restrict__ sums2) {
    __shared__ double red[128];
    int t = threadIdx.x;          // 128 threads = 2 waves (ci = t)
    int blk = blockIdx.x;         // 256 blocks
    int lane = t & 63;
    int wv = t >> 6;              // wave 0: ci 0..63 (words 0,1); wave 1: ci 64..127 (words 2,3)
    if (blk == 0) {
        sums1[t] = 0.0; sums1[128 + t] = 0.0;
        sums2[t] = 0.0; sums2[128 + t] = 0.0;
    }
    if (blk < 128) {
        int o = blk;
        double acc = 0.0;
        #pragma unroll
        for (int j = 0; j < 9; ++j) {
            float v = w3[o * 1152 + t * 9 + j];     // [o][ci=t][tap=j]
            acc += fabs((double)v);
            unsigned long long b = __ballot(v > 0.f);
            if (lane == 0) {
                wbits3[o * W3STRIDE + j * 4 + wv * 2 + 0] = (uint_t)b;
                wbits3[o * W3STRIDE + j * 4 + wv * 2 + 1] = (uint_t)(b >> 32);
            }
        }
        red[t] = acc; __syncthreads();
        for (int s = 64; s > 0; s >>= 1) { if (t < s) red[t] += red[t + s]; __syncthreads(); }
        if (t == 0) scale3[o] = red[0] / 1152.0;
    } else {
        int o = blk - 128;
        float v = w1[o * 128 + t];
        unsigned long long b = __ballot(v > 0.f);
        if (lane == 0) {
            wbits1[o * W1STRIDE + wv * 2 + 0] = (uint_t)b;
            wbits1[o * W1STRIDE + wv * 2 + 1] = (uint_t)(b >> 32);
        }
        red[t] = fabs((double)v); __syncthreads();
        for (int s = 64; s > 0; s >>= 1) { if (t < s) red[t] += red[t + s]; __syncthreads(); }
        if (t == 0) scale1[o] = red[0] / 128.0;
    }
}

// ---------------------------------------------------------------------------
// sign1: pack sign(x_shuffled + b1) into bit planes.
// vb/mb layout: [word 0..7][NPIX] where word = c>>5, bit = c&31.
// Phase 1: coalesced 64pix x 64ch tile load -> sign code in LDS.
// Phase 2: lanes = channels, __ballot -> 2 v-dwords + 2 m-dwords per pixel.
// ---------------------------------------------------------------------------
__global__ void sign1_kernel(const float* __restrict__ x, const float* __restrict__ b1,
                             uint_t* __restrict__ vb, uint_t* __restrict__ mb) {
    __shared__ uint_t tile[64 * 65];
    int t = threadIdx.x;
    int p0 = blockIdx.x * 64;
    int c0 = blockIdx.y * 64;
    int b = p0 / HW_N;
    int hw0 = p0 % HW_N;     // 3136 % 64 == 0 -> tile stays in one image
    #pragma unroll 4
    for (int it = 0; it < 16; ++it) {
        int idx = it * 256 + t;
        int pl = idx & 63, cl = idx >> 6;
        int c = c0 + cl;
        int src = ((c & 1) << 7) + (c >> 1);
        double v = (double)x[((size_t)b * C_N + src) * HW_N + hw0 + pl] + (double)b1[c];
        tile[cl * 65 + pl] = (v > 0.0 ? 1u : 0u) | (v != 0.0 ? 2u : 0u);
    }
    __syncthreads();
    int lane = t & 63;
    int wv = t >> 6;
    int w0 = c0 >> 5;
    #pragma unroll 4
    for (int i = 0; i < 16; ++i) {
        int pl = wv * 16 + i;
        uint_t cell = tile[lane * 65 + pl];
        unsigned long long bv = __ballot((cell & 1u) != 0u);
        unsigned long long bm = __ballot((cell & 2u) != 0u);
        if (lane < 4) {
            unsigned long long srcb = (lane & 2) ? bm : bv;
            uint_t dw = (lane & 1) ? (uint_t)(srcb >> 32) : (uint_t)srcb;
            uint_t* basep = (lane & 2) ? mb : vb;
            basep[(size_t)(w0 + (lane & 1)) * NPIX + p0 + pl] = dw;
        }
    }
}

// ---------------------------------------------------------------------------
// conv3: grouped 3x3 binary conv via XOR/popcount.
// Thread = 1 pixel, grid (NPIX/256, 2 groups). Signs (9 taps x 4 words,
// v+m) in VGPRs; 64 out-ch loop with wave-uniform scalar weights.
// dot = popc(m) - 2*popc((v^w)&m).  Output y[o][p] fp16 (exact ints).
// ---------------------------------------------------------------------------
__global__ __launch_bounds__(256) void conv3_kernel(const uint_t* __restrict__ vb,
                                                    const uint_t* __restrict__ mb,
                                                    const uint_t* __restrict__ wbits3,
                                                    half_t* __restrict__ yh) {
    int g = blockIdx.y;
    int p = blockIdx.x * 256 + threadIdx.x;
    int hw = p % HW_N;
    int h = hw / W_N;
    int w = hw - h * W_N;
    const uint_t* vbase = vb + (size_t)g * 4 * NPIX;
    const uint_t* mbase = mb + (size_t)g * 4 * NPIX;

    uint_t v[9][4], m[9][4];
    #pragma unroll
    for (int j = 0; j < 9; ++j) {
        int kh = j / 3 - 1, kw = j % 3 - 1;
        int hh = h + kh, ww = w + kw;
        bool valid = (hh >= 0) && (hh < H_N) && (ww >= 0) && (ww < W_N);
        int off = p + kh * W_N + kw;
        #pragma unroll
        for (int q = 0; q < 4; ++q) {
            v[j][q] = valid ? vbase[(size_t)q * NPIX + off] : 0u;
            m[j][q] = valid ? mbase[(size_t)q * NPIX + off] : 0u;
        }
    }
    int Km = 0;
    #pragma unroll
    for (int j = 0; j < 9; ++j)
        #pragma unroll
        for (int q = 0; q < 4; ++q) Km += __popc(m[j][q]);

    const uint_t* wrow = wbits3 + (size_t)g * 64 * W3STRIDE;
    half_t* yrow = yh + (size_t)g * 64 * NPIX + p;
    for (int o = 0; o < 64; ++o) {
        const uint_t* wo = wrow + o * W3STRIDE;
        int acc = 0;
        #pragma unroll
        for (int j = 0; j < 9; ++j)
            #pragma unroll
            for (int q = 0; q < 4; ++q)
                acc += __popc((v[j][q] ^ wo[j * 4 + q]) & m[j][q]);
        int dot = Km - 2 * acc;
        yrow[(size_t)o * NPIX] = (half_t)(float)dot;
    }
}

// ---------------------------------------------------------------------------
// conv1: grouped 1x1 binary conv via XOR/popcount (K=128 = 4 words).
// ---------------------------------------------------------------------------
__global__ __launch_bounds__(256) void conv1_kernel(const uint_t* __restrict__ vb,
                                                    const uint_t* __restrict__ mb,
                                                    const uint_t* __restrict__ wbits1,
                                                    half_t* __restrict__ yh) {
    int g = blockIdx.y;
    int p = blockIdx.x * 256 + threadIdx.x;
    uint_t v[4], m[4];
    #pragma unroll
    for (int q = 0; q < 4; ++q) {
        v[q] = vb[(size_t)(g * 4 + q) * NPIX + p];
        m[q] = mb[(size_t)(g * 4 + q) * NPIX + p];
    }
    int Km = __popc(m[0]) + __popc(m[1]) + __popc(m[2]) + __popc(m[3]);
    const uint_t* wrow = wbits1 + (size_t)g * 64 * W1STRIDE;
    half_t* yrow = yh + (size_t)g * 64 * NPIX + p;
    for (int o = 0; o < 64; ++o) {
        const uint_t* wo = wrow + o * W1STRIDE;
        int acc = 0;
        #pragma unroll
        for (int q = 0; q < 4; ++q) acc += __popc((v[q] ^ wo[q]) & m[q]);
        yrow[(size_t)o * NPIX] = (half_t)(float)(Km - 2 * acc);
    }
}

// ---------------------------------------------------------------------------
// stats: per-channel sum / sumsq (fp64 exact; y values are exact ints).
// ---------------------------------------------------------------------------
__global__ void stats_kernel(const half_t* __restrict__ yh, double* __restrict__ sums) {
    __shared__ double sh[512];
    int t = threadIdx.x;
    int c = blockIdx.x & 127;
    int chunk = blockIdx.x >> 7;
    const half_t* p = yh + (size_t)c * NPIX + chunk * 12544;
    double s = 0.0, s2 = 0.0;
    for (int i = t; i < 12544; i += 256) {
        double d = (double)(float)p[i];
        s += d; s2 += d * d;
    }
    sh[t] = s; sh[256 + t] = s2;
    __syncthreads();
    for (int k = 128; k > 0; k >>= 1) {
        if (t < k) { sh[t] += sh[t + k]; sh[256 + t] += sh[256 + t + k]; }
        __syncthreads();
    }
    if (t == 0) { atomicAdd(&sums[c], sh[0]); atomicAdd(&sums[128 + c], sh[256]); }
}

// ---------------------------------------------------------------------------
// finalize: fold weight scale + BN into affine coef (fp64).
// ---------------------------------------------------------------------------
__global__ void finalize_kernel(const double* __restrict__ sums, const double* __restrict__ scale,
                                const float* __restrict__ gamma, const float* __restrict__ beta,
                                double* __restrict__ coef) {
    int c = threadIdx.x;  // 128
    double M = (double)NPIX;
    double mean = sums[c] / M;
    double var = sums[128 + c] / M - mean * mean;
    double s = scale[c];
    double r = 1.0 / sqrt(s * s * var + EPS_D);
    double g = (double)gamma[c];
    coef[c] = s * r * g;
    coef[128 + c] = (double)beta[c] - s * mean * r * g;
}

// ---------------------------------------------------------------------------
// x2 value chain (fp64, deterministic; used bit-identically in x2s_kernel
// and out_kernel so conv1's signs stay consistent with the epilogue).
// ---------------------------------------------------------------------------
__device__ __forceinline__ double x2_val(double xs, double K, bool hasy,
                                         const double* __restrict__ coef1, int c,
                                         const float* __restrict__ b2_1, const float* __restrict__ a2,
                                         const float* __restrict__ b2_2, const float* __restrict__ b3_1) {
    double t = hasy ? (coef1[c] * K + coef1[128 + c] + xs) : xs;
    t += (double)b2_1[c];
    double a = (double)a2[c];
    t = (t >= 0.0) ? t : a * t;
    t += (double)b2_2[c];
    t += (double)b3_1[c];
    return t;
}

// ---------------------------------------------------------------------------
// x2s: recompute x2 (fp64) and pack sign(x2) into bit planes (ballot).
// ---------------------------------------------------------------------------
__global__ void x2s_kernel(const float* __restrict__ x, const half_t* __restrict__ y1h,
                           const double* __restrict__ coef1,
                           const float* __restrict__ b2_1, const float* __restrict__ a2,
                           const float* __restrict__ b2_2, const float* __restrict__ b3_1,
                           uint_t* __restrict__ vb, uint_t* __restrict__ mb) {
    __shared__ uint_t tile[64 * 65];
    int t = threadIdx.x;
    int p0 = blockIdx.x * 64;
    int c0 = blockIdx.y * 64;
    int b = p0 / HW_N;
    int hw0 = p0 % HW_N;
    #pragma unroll 4
    for (int it = 0; it < 16; ++it) {
        int idx = it * 256 + t;
        int pl = idx & 63, cl = idx >> 6;
        int c = c0 + cl;
        int src = ((c & 1) << 7) + (c >> 1);
        int p = p0 + pl;
        double xs = (double)x[((size_t)b * C_N + src) * HW_N + hw0 + pl];
        bool hasy = (c < 128);
        double K = hasy ? (double)(float)y1h[(size_t)c * NPIX + p] : 0.0;
        double v = x2_val(xs, K, hasy, coef1, c, b2_1, a2, b2_2, b3_1);
        tile[cl * 65 + pl] = (v > 0.0 ? 1u : 0u) | (v != 0.0 ? 2u : 0u);
    }
    __syncthreads();
    int lane = t & 63;
    int wv = t >> 6;
    int w0 = c0 >> 5;
    #pragma unroll 4
    for (int i = 0; i < 16; ++i) {
        int pl = wv * 16 + i;
        uint_t cell = tile[lane * 65 + pl];
        unsigned long long bv = __ballot((cell & 1u) != 0u);
        unsigned long long bm = __ballot((cell & 2u) != 0u);
        if (lane < 4) {
            unsigned long long srcb = (lane & 2) ? bm : bv;
            uint_t dw = (lane & 1) ? (uint_t)(srcb >> 32) : (uint_t)srcb;
            uint_t* basep = (lane & 2) ? mb : vb;
            basep[(size_t)(w0 + (lane & 1)) * NPIX + p0 + pl] = dw;
        }
    }
}

// ---------------------------------------------------------------------------
// out: recompute x2 (same fp64 expr), x3 = BN3(y3)+x2[:, :128], concat,
// prelu(+b4_1, a4)+b4_2, write NCHW fp32. Fully coalesced.
// ---------------------------------------------------------------------------
__global__ void out_kernel(const float* __restrict__ x, const half_t* __restrict__ y1h,
                           const half_t* __restrict__ y3h,
                           const double* __restrict__ coef1, const double* __restrict__ coef3,
                           const float* __restrict__ b2_1, const float* __restrict__ a2,
                           const float* __restrict__ b2_2, const float* __restrict__ b3_1,
                           const float* __restrict__ b4_1, const float* __restrict__ a4,
                           const float* __restrict__ b4_2, float* __restrict__ out) {
    int t = threadIdx.x;
    int c = blockIdx.y;
    int p = blockIdx.x * 256 + t;
    int b = p / HW_N;
    int hw = p % HW_N;
    int src = ((c & 1) << 7) + (c >> 1);
    double xs = (double)x[((size_t)b * C_N + src) * HW_N + hw];
    bool h1 = (c < 128);
    double K1 = h1 ? (double)(float)y1h[(size_t)c * NPIX + p] : 0.0;
    double t2 = x2_val(xs, K1, h1, coef1, c, b2_1, a2, b2_2, b3_1);
    double v = t2;
    if (h1) v = coef3[c] * (double)(float)y3h[(size_t)c * NPIX + p] + coef3[128 + c] + t2;
    v += (double)b4_1[c];
    double a = (double)a4[c];
    v = (v >= 0.0) ? v : a * v;
    v += (double)b4_2[c];
    out[((size_t)b * C_N + c) * HW_N + hw] = (float)v;
}

extern "C" void kernel_launch(void* const* d_in, const int* in_sizes, int n_in,
                              void* d_out, int out_size, void* d_ws, size_t ws_size,
                              hipStream_t stream) {
    const float* x    = (const float*)d_in[0];
    const float* w3   = (const float*)d_in[1];
    const float* w1   = (const float*)d_in[2];
    const float* b1   = (const float*)d_in[3];
    const float* g1   = (const float*)d_in[4];
    const float* be1  = (const float*)d_in[5];
    const float* b2_1 = (const float*)d_in[6];
    const float* a2   = (const float*)d_in[7];
    const float* b2_2 = (const float*)d_in[8];
    const float* b3_1 = (const float*)d_in[9];
    const float* g3   = (const float*)d_in[10];
    const float* be3  = (const float*)d_in[11];
    const float* b4_1 = (const float*)d_in[12];
    const float* a4   = (const float*)d_in[13];
    const float* b4_2 = (const float*)d_in[14];

    // workspace (~51.5 MB)
    char* ws = (char*)d_ws;
    half_t* y1h    = (half_t*)(ws + 0);                 // 25,690,112
    half_t* y3h    = (half_t*)(ws + 25690112);          // 25,690,112
    uint_t* wbits3 = (uint_t*)(ws + 51380224);          // 128*48*4 = 24,576
    uint_t* wbits1 = (uint_t*)(ws + 51404800);          // 128*8*4 = 4,096
    double* scale3 = (double*)(ws + 51408896);          // 1,024
    double* scale1 = (double*)(ws + 51409920);          // 1,024
    double* sums1  = (double*)(ws + 51410944);          // 2,048
    double* sums2  = (double*)(ws + 51412992);          // 2,048
    double* coef1  = (double*)(ws + 51415040);          // 2,048
    double* coef3  = (double*)(ws + 51417088);          // 2,048

    // packed sign planes (12.8 MB) live in d_out (102.7 MB fp32);
    // all consumed before out_kernel overwrites d_out.
    uint_t* vb1 = (uint_t*)((char*)d_out + 0);          // 8*NPIX*4 = 3,211,264
    uint_t* mb1 = (uint_t*)((char*)d_out + 3211264);
    uint_t* vb2 = (uint_t*)((char*)d_out + 6422528);
    uint_t* mb2 = (uint_t*)((char*)d_out + 9633792);
    float*  outp = (float*)d_out;

    prep_kernel<<<256, 128, 0, stream>>>(w3, w1, wbits3, wbits1, scale3, scale1, sums1, sums2);
    sign1_kernel<<<dim3(NPIX / 64, 4), 256, 0, stream>>>(x, b1, vb1, mb1);
    conv3_kernel<<<dim3(NPIX / 256, 2), 256, 0, stream>>>(vb1, mb1, wbits3, y1h);
    stats_kernel<<<1024, 256, 0, stream>>>(y1h, sums1);
    finalize_kernel<<<1, 128, 0, stream>>>(sums1, scale3, g1, be1, coef1);
    x2s_kernel<<<dim3(NPIX / 64, 4), 256, 0, stream>>>(x, y1h, coef1, b2_1, a2, b2_2, b3_1, vb2, mb2);
    conv1_kernel<<<dim3(NPIX / 256, 2), 256, 0, stream>>>(vb2, mb2, wbits1, y3h);
    stats_kernel<<<1024, 256, 0, stream>>>(y3h, sums2);
    finalize_kernel<<<1, 128, 0, stream>>>(sums2, scale1, g3, be3, coef3);
    out_kernel<<<dim3(NPIX / 256, 256), 256, 0, stream>>>(x, y1h, y3h, coef1, coef3,
                                                          b2_1, a2, b2_2, b3_1, b4_1, a4, b4_2, outp);
}

// Round 4
// 387.514 us; speedup vs baseline: 1.6791x; 1.1643x over previous
//
#include <hip/hip_runtime.h>
#include <stdint.h>

typedef unsigned short ushort_t;
typedef unsigned int uint_t;
typedef _Float16 half_t;

#define B_N 32
#define C_N 256
#define HALF_N 128
#define H_N 56
#define W_N 56
#define HW_N 3136
#define NPIX (B_N * HW_N)   // 100352
#define EPS_D 1e-5
#define W3S 40              // dwords per out-ch for 3x3 bits (36 used)
#define PWS 16              // dwords per out-ch for per-tap popcounts (9 used)

// ---------------------------------------------------------------------------
// prep: pack weight sign bits (bit=1 iff w>0; w<=0 -> -1) + per-(o,tap)
// popcounts for padding correction + fp64 scales. Block 0 zeroes stats.
// wbits3[o*W3S + tap*4 + word], word = ci>>5.  popcw3[o*PWS + tap].
// ---------------------------------------------------------------------------
__global__ void prep_kernel(const float* __restrict__ w3, const float* __restrict__ w1,
                            uint_t* __restrict__ wbits3, uint_t* __restrict__ wbits1,
                            uint_t* __restrict__ popcw3,
                            double* __restrict__ scale3, double* __restrict__ scale1,
                            double* __restrict__ sums1, double* __restrict__ sums2) {
    __shared__ double red[128];
    __shared__ int ipw[2][9];
    int t = threadIdx.x;          // 128 threads = 2 waves (ci = t)
    int blk = blockIdx.x;         // 256 blocks
    int lane = t & 63;
    int wv = t >> 6;
    if (blk == 0) {
        sums1[t] = 0.0; sums1[128 + t] = 0.0;
        sums2[t] = 0.0; sums2[128 + t] = 0.0;
    }
    if (blk < 128) {
        int o = blk;
        double acc = 0.0;
        #pragma unroll
        for (int j = 0; j < 9; ++j) {
            float v = w3[o * 1152 + t * 9 + j];     // [o][ci=t][tap=j]
            acc += fabs((double)v);
            unsigned long long b = __ballot(v > 0.f);
            if (lane == 0) {
                wbits3[o * W3S + j * 4 + wv * 2 + 0] = (uint_t)b;
                wbits3[o * W3S + j * 4 + wv * 2 + 1] = (uint_t)(b >> 32);
                ipw[wv][j] = __popcll(b);
            }
        }
        red[t] = acc; __syncthreads();
        for (int s = 64; s > 0; s >>= 1) { if (t < s) red[t] += red[t + s]; __syncthreads(); }
        if (t == 0) scale3[o] = red[0] / 1152.0;
        if (t < 9) popcw3[o * PWS + t] = (uint_t)(ipw[0][t] + ipw[1][t]);
    } else {
        int o = blk - 128;
        float v = w1[o * 128 + t];
        unsigned long long b = __ballot(v > 0.f);
        if (lane == 0) {
            wbits1[o * 8 + wv * 2 + 0] = (uint_t)b;
            wbits1[o * 8 + wv * 2 + 1] = (uint_t)(b >> 32);
        }
        red[t] = fabs((double)v); __syncthreads();
        for (int s = 64; s > 0; s >>= 1) { if (t < s) red[t] += red[t + s]; __syncthreads(); }
        if (t == 0) scale1[o] = red[0] / 128.0;
    }
}

// ---------------------------------------------------------------------------
// sign1: pack (x_shuffled + b1 > 0) into bit planes vb[word 0..7][NPIX],
// word = c>>5.  Phase 1: coalesced tile -> LDS; phase 2: ballot.
// ---------------------------------------------------------------------------
__global__ void sign1_kernel(const float* __restrict__ x, const float* __restrict__ b1,
                             uint_t* __restrict__ vb) {
    __shared__ uint_t tile[64 * 65];
    int t = threadIdx.x;
    int p0 = blockIdx.x * 64;
    int c0 = blockIdx.y * 64;
    int b = p0 / HW_N;
    int hw0 = p0 % HW_N;     // 3136 % 64 == 0 -> tile stays in one image
    #pragma unroll 4
    for (int it = 0; it < 16; ++it) {
        int idx = it * 256 + t;
        int pl = idx & 63, cl = idx >> 6;
        int c = c0 + cl;
        int src = ((c & 1) << 7) + (c >> 1);
        double v = (double)x[((size_t)b * C_N + src) * HW_N + hw0 + pl] + (double)b1[c];
        tile[cl * 65 + pl] = (v > 0.0) ? 1u : 0u;
    }
    __syncthreads();
    int lane = t & 63;
    int wv = t >> 6;
    int w0 = c0 >> 5;
    #pragma unroll 4
    for (int i = 0; i < 16; ++i) {
        int pl = wv * 16 + i;
        unsigned long long bv = __ballot(tile[lane * 65 + pl] != 0u);
        if (lane < 2) {
            uint_t dw = lane ? (uint_t)(bv >> 32) : (uint_t)bv;
            vb[(size_t)(w0 + lane) * NPIX + p0 + pl] = dw;
        }
    }
}

// ---------------------------------------------------------------------------
// conv3 + fused stats: grouped 3x3 binary conv via XOR/popcount.
// Grid (392, 4): by>>1 = group, by&1 = o-half (32 out-ch per thread).
// dot = 128*nvalid - 2*acc + 2*corr, corr = sum_{invalid tap} popcw[o][tap].
// Per-o wave reduction of (dot, dot^2) -> LDS -> fp64 atomics (exact ints).
// ---------------------------------------------------------------------------
__global__ __launch_bounds__(256) void conv3_kernel(const uint_t* __restrict__ vb,
                                                    const uint_t* __restrict__ wbits3,
                                                    const uint_t* __restrict__ popcw3,
                                                    half_t* __restrict__ yh,
                                                    double* __restrict__ sums) {
    __shared__ int ldsS[4][32];
    __shared__ int ldsS2[4][32];
    int t = threadIdx.x;
    int lane = t & 63;
    int wv = t >> 6;
    int g = blockIdx.y >> 1;
    int oh = blockIdx.y & 1;
    int o0 = g * 64 + oh * 32;
    int p = blockIdx.x * 256 + t;
    int hw = p % HW_N;
    int h = hw / W_N;
    int w = hw - h * W_N;
    const uint_t* vbase = vb + (size_t)g * 4 * NPIX;

    uint_t v[9][4];
    int inv[9];
    int nvalid = 0;
    #pragma unroll
    for (int j = 0; j < 9; ++j) {
        int kh = j / 3 - 1, kw = j - (j / 3) * 3 - 1;
        int hh = h + kh, ww = w + kw;
        bool valid = (hh >= 0) && (hh < H_N) && (ww >= 0) && (ww < W_N);
        inv[j] = valid ? 0 : 1;
        nvalid += valid ? 1 : 0;
        int off = p + kh * W_N + kw;
        #pragma unroll
        for (int q = 0; q < 4; ++q)
            v[j][q] = valid ? vbase[(size_t)q * NPIX + off] : 0u;
    }
    int base = 128 * nvalid;

    half_t* yrow = yh + (size_t)o0 * NPIX + p;
    for (int oi = 0; oi < 32; ++oi) {
        const uint_t* wo = wbits3 + (size_t)(o0 + oi) * W3S;
        const uint_t* pw = popcw3 + (size_t)(o0 + oi) * PWS;
        int acc = 0;
        #pragma unroll
        for (int j = 0; j < 9; ++j)
            #pragma unroll
            for (int q = 0; q < 4; ++q)
                acc += __popc(v[j][q] ^ wo[j * 4 + q]);
        int corr = 0;
        #pragma unroll
        for (int j = 0; j < 9; ++j) corr += inv[j] * (int)pw[j];
        int dot = base - 2 * (acc - corr);
        yrow[(size_t)oi * NPIX] = (half_t)(float)dot;
        int s = dot, s2 = dot * dot;
        #pragma unroll
        for (int off = 32; off > 0; off >>= 1) {
            s  += __shfl_xor(s, off);
            s2 += __shfl_xor(s2, off);
        }
        if (lane == 0) { ldsS[wv][oi] = s; ldsS2[wv][oi] = s2; }
    }
    __syncthreads();
    if (t < 32) {
        int S  = ldsS[0][t] + ldsS[1][t] + ldsS[2][t] + ldsS[3][t];
        int S2 = ldsS2[0][t] + ldsS2[1][t] + ldsS2[2][t] + ldsS2[3][t];
        int c = o0 + t;
        atomicAdd(&sums[c], (double)S);
        atomicAdd(&sums[128 + c], (double)S2);
    }
}

// ---------------------------------------------------------------------------
// conv1 + fused stats: grouped 1x1 binary conv (K=128, no padding).
// ---------------------------------------------------------------------------
__global__ __launch_bounds__(256) void conv1_kernel(const uint_t* __restrict__ vb,
                                                    const uint_t* __restrict__ wbits1,
                                                    half_t* __restrict__ yh,
                                                    double* __restrict__ sums) {
    __shared__ int ldsS[4][64];
    __shared__ int ldsS2[4][64];
    int t = threadIdx.x;
    int lane = t & 63;
    int wv = t >> 6;
    int g = blockIdx.y;
    int p = blockIdx.x * 256 + t;
    uint_t v[4];
    #pragma unroll
    for (int q = 0; q < 4; ++q) v[q] = vb[(size_t)(g * 4 + q) * NPIX + p];

    half_t* yrow = yh + (size_t)g * 64 * NPIX + p;
    const uint_t* wrow = wbits1 + (size_t)g * 64 * 8;
    for (int o = 0; o < 64; ++o) {
        const uint_t* wo = wrow + o * 8;
        int acc = 0;
        #pragma unroll
        for (int q = 0; q < 4; ++q) acc += __popc(v[q] ^ wo[q]);
        int dot = 128 - 2 * acc;
        yrow[(size_t)o * NPIX] = (half_t)(float)dot;
        int s = dot, s2 = dot * dot;
        #pragma unroll
        for (int off = 32; off > 0; off >>= 1) {
            s  += __shfl_xor(s, off);
            s2 += __shfl_xor(s2, off);
        }
        if (lane == 0) { ldsS[wv][o] = s; ldsS2[wv][o] = s2; }
    }
    __syncthreads();
    if (t < 64) {
        int S  = ldsS[0][t] + ldsS[1][t] + ldsS[2][t] + ldsS[3][t];
        int S2 = ldsS2[0][t] + ldsS2[1][t] + ldsS2[2][t] + ldsS2[3][t];
        int c = g * 64 + t;
        atomicAdd(&sums[c], (double)S);
        atomicAdd(&sums[128 + c], (double)S2);
    }
}

// ---------------------------------------------------------------------------
// coef entry (fp64): identical expression everywhere -> bit-identical coefs.
// ---------------------------------------------------------------------------
__device__ __forceinline__ void coef_entry(const double* __restrict__ sums,
                                           const double* __restrict__ scale,
                                           const float* __restrict__ gamma,
                                           const float* __restrict__ beta,
                                           int c, double* coefL) {
    double M = (double)NPIX;
    double mean = sums[c] / M;
    double var = sums[128 + c] / M - mean * mean;
    double s = scale[c];
    double r = 1.0 / sqrt(s * s * var + EPS_D);
    double g = (double)gamma[c];
    coefL[c] = s * r * g;
    coefL[128 + c] = (double)beta[c] - s * mean * r * g;
}

// ---------------------------------------------------------------------------
// x2 value chain (fp64, deterministic; bit-identical in x2s and out).
// ---------------------------------------------------------------------------
__device__ __forceinline__ double x2_val(double xs, double K, bool hasy,
                                         const double* coef1, int c,
                                         const float* __restrict__ b2_1, const float* __restrict__ a2,
                                         const float* __restrict__ b2_2, const float* __restrict__ b3_1) {
    double t = hasy ? (coef1[c] * K + coef1[128 + c] + xs) : xs;
    t += (double)b2_1[c];
    double a = (double)a2[c];
    t = (t >= 0.0) ? t : a * t;
    t += (double)b2_2[c];
    t += (double)b3_1[c];
    return t;
}

// ---------------------------------------------------------------------------
// x2s: compute coef1 in-block (from sums1), recompute x2 (fp64), pack
// sign(x2) bit plane via ballot.
// ---------------------------------------------------------------------------
__global__ void x2s_kernel(const float* __restrict__ x, const half_t* __restrict__ y1h,
                           const double* __restrict__ sums1, const double* __restrict__ scale3,
                           const float* __restrict__ g1, const float* __restrict__ be1,
                           const float* __restrict__ b2_1, const float* __restrict__ a2,
                           const float* __restrict__ b2_2, const float* __restrict__ b3_1,
                           uint_t* __restrict__ vb) {
    __shared__ uint_t tile[64 * 65];
    __shared__ double coefL[256];
    int t = threadIdx.x;
    if (t < 128) coef_entry(sums1, scale3, g1, be1, t, coefL);
    __syncthreads();
    int p0 = blockIdx.x * 64;
    int c0 = blockIdx.y * 64;
    int b = p0 / HW_N;
    int hw0 = p0 % HW_N;
    #pragma unroll 4
    for (int it = 0; it < 16; ++it) {
        int idx = it * 256 + t;
        int pl = idx & 63, cl = idx >> 6;
        int c = c0 + cl;
        int src = ((c & 1) << 7) + (c >> 1);
        int p = p0 + pl;
        double xs = (double)x[((size_t)b * C_N + src) * HW_N + hw0 + pl];
        bool hasy = (c < 128);
        double K = hasy ? (double)(float)y1h[(size_t)c * NPIX + p] : 0.0;
        double v = x2_val(xs, K, hasy, coefL, c, b2_1, a2, b2_2, b3_1);
        tile[cl * 65 + pl] = (v > 0.0) ? 1u : 0u;
    }
    __syncthreads();
    int lane = t & 63;
    int wv = t >> 6;
    int w0 = c0 >> 5;
    #pragma unroll 4
    for (int i = 0; i < 16; ++i) {
        int pl = wv * 16 + i;
        unsigned long long bv = __ballot(tile[lane * 65 + pl] != 0u);
        if (lane < 2) {
            uint_t dw = lane ? (uint_t)(bv >> 32) : (uint_t)bv;
            vb[(size_t)(w0 + lane) * NPIX + p0 + pl] = dw;
        }
    }
}

// ---------------------------------------------------------------------------
// out: compute coef1+coef3 in-block, recompute x2 (same fp64 expr),
// x3 = BN3(y3)+x2[:, :128], concat, prelu(+b4_1,a4)+b4_2, write NCHW fp32.
// 8 pixels per thread.
// ---------------------------------------------------------------------------
__global__ void out_kernel(const float* __restrict__ x, const half_t* __restrict__ y1h,
                           const half_t* __restrict__ y3h,
                           const double* __restrict__ sums1, const double* __restrict__ scale3,
                           const float* __restrict__ g1, const float* __restrict__ be1,
                           const double* __restrict__ sums2, const double* __restrict__ scale1,
                           const float* __restrict__ g3, const float* __restrict__ be3,
                           const float* __restrict__ b2_1, const float* __restrict__ a2,
                           const float* __restrict__ b2_2, const float* __restrict__ b3_1,
                           const float* __restrict__ b4_1, const float* __restrict__ a4,
                           const float* __restrict__ b4_2, float* __restrict__ out) {
    __shared__ double c1L[256];
    __shared__ double c3L[256];
    int t = threadIdx.x;
    if (t < 128) coef_entry(sums1, scale3, g1, be1, t, c1L);
    else coef_entry(sums2, scale1, g3, be3, t - 128, c3L);
    __syncthreads();
    int c = blockIdx.y;
    bool h1 = (c < 128);
    int src = ((c & 1) << 7) + (c >> 1);
    double b41 = (double)b4_1[c];
    double a = (double)a4[c];
    double b42 = (double)b4_2[c];
    #pragma unroll
    for (int i = 0; i < 8; ++i) {
        int p = blockIdx.x * 2048 + i * 256 + t;
        int b = p / HW_N;
        int hw = p % HW_N;
        double xs = (double)x[((size_t)b * C_N + src) * HW_N + hw];
        double K1 = h1 ? (double)(float)y1h[(size_t)c * NPIX + p] : 0.0;
        double t2 = x2_val(xs, K1, h1, c1L, c, b2_1, a2, b2_2, b3_1);
        double v = t2;
        if (h1) v = c3L[c] * (double)(float)y3h[(size_t)c * NPIX + p] + c3L[128 + c] + t2;
        v += b41;
        v = (v >= 0.0) ? v : a * v;
        v += b42;
        out[((size_t)b * C_N + c) * HW_N + hw] = (float)v;
    }
}

extern "C" void kernel_launch(void* const* d_in, const int* in_sizes, int n_in,
                              void* d_out, int out_size, void* d_ws, size_t ws_size,
                              hipStream_t stream) {
    const float* x    = (const float*)d_in[0];
    const float* w3   = (const float*)d_in[1];
    const float* w1   = (const float*)d_in[2];
    const float* b1   = (const float*)d_in[3];
    const float* g1   = (const float*)d_in[4];
    const float* be1  = (const float*)d_in[5];
    const float* b2_1 = (const float*)d_in[6];
    const float* a2   = (const float*)d_in[7];
    const float* b2_2 = (const float*)d_in[8];
    const float* b3_1 = (const float*)d_in[9];
    const float* g3   = (const float*)d_in[10];
    const float* be3  = (const float*)d_in[11];
    const float* b4_1 = (const float*)d_in[12];
    const float* a4   = (const float*)d_in[13];
    const float* b4_2 = (const float*)d_in[14];

    // workspace (~51.5 MB)
    char* ws = (char*)d_ws;
    half_t* y1h    = (half_t*)(ws + 0);                 // 25,690,112
    half_t* y3h    = (half_t*)(ws + 25690112);          // 25,690,112
    uint_t* wbits3 = (uint_t*)(ws + 51380224);          // 128*40*4 = 20,480
    uint_t* wbits1 = (uint_t*)(ws + 51400704);          // 128*8*4 = 4,096
    uint_t* popcw3 = (uint_t*)(ws + 51404800);          // 128*16*4 = 8,192
    double* scale3 = (double*)(ws + 51412992);          // 1,024
    double* scale1 = (double*)(ws + 51414016);          // 1,024
    double* sums1  = (double*)(ws + 51415040);          // 2,048
    double* sums2  = (double*)(ws + 51417088);          // 2,048

    // packed sign planes (2 x 3.2 MB) live in d_out (102.7 MB fp32);
    // consumed before out_kernel overwrites d_out.
    uint_t* vb1 = (uint_t*)((char*)d_out + 0);          // 8*NPIX*4 = 3,211,264
    uint_t* vb2 = (uint_t*)((char*)d_out + 3211264);
    float*  outp = (float*)d_out;

    prep_kernel<<<256, 128, 0, stream>>>(w3, w1, wbits3, wbits1, popcw3,
                                         scale3, scale1, sums1, sums2);
    sign1_kernel<<<dim3(NPIX / 64, 4), 256, 0, stream>>>(x, b1, vb1);
    conv3_kernel<<<dim3(NPIX / 256, 4), 256, 0, stream>>>(vb1, wbits3, popcw3, y1h, sums1);
    x2s_kernel<<<dim3(NPIX / 64, 4), 256, 0, stream>>>(x, y1h, sums1, scale3, g1, be1,
                                                       b2_1, a2, b2_2, b3_1, vb2);
    conv1_kernel<<<dim3(NPIX / 256, 2), 256, 0, stream>>>(vb2, wbits1, y3h, sums2);
    out_kernel<<<dim3(NPIX / 2048, 256), 256, 0, stream>>>(x, y1h, y3h,
                                                           sums1, scale3, g1, be1,
                                                           sums2, scale1, g3, be3,
                                                           b2_1, a2, b2_2, b3_1,
                                                           b4_1, a4, b4_2, outp);
}